// Round 12
// baseline (137.163 us; speedup 1.0000x reference)
//
#include <hip/hip_runtime.h>
#include <hip/hip_bf16.h>

// RelativeSemanticLoss via bf16 MFMA GEMM + fused softmax-NLL epilogue.
// R12: DRAM-granularity test. BM=256 px, BK=16, 32x32x16 MFMA (R5-verified
// fragment maps/epilogue). Every global_load_lds instruction now reads
// 1 KB CONTIGUOUS within one dim (vs 2x512B before). 2-phase dbuf attractor.

#define NUM_CLS 150
#define NT_TILES 5       // 5 x 32 = 160 padded classes
#define D_DIM   512
#define HW_DIM  65536
#define IGNORE_L 255

typedef __attribute__((ext_vector_type(8)))  short bf16x8;
typedef __attribute__((ext_vector_type(16))) float f32x16;
typedef __attribute__((ext_vector_type(4)))  unsigned int u32x4;

#define GLOAD16(gsrc, ldst) \
    __builtin_amdgcn_global_load_lds((const __attribute__((address_space(1))) void*)(gsrc), \
                                     (__attribute__((address_space(3))) void*)(ldst), 16, 0, 0)

static __device__ __forceinline__ short f2bf(float f) {
    __hip_bfloat16 h = __float2bfloat16(f);   // RNE
    return __builtin_bit_cast(short, h);
}

// Pack cls (150x512 fp32) -> bf16 32x32x16 B-fragments, lane-linear (R5-verified):
// packed[(s2*5+nt)*512 + l*8 + j] = bf16(cls[nt*32+(l&31)][s2*16+(l>>5)*8+j])
// s2 = 0..31 (K-steps of 16). Also zeroes ws accumulators.
__global__ void rsl_pack_cls(const float* __restrict__ cls,
                             unsigned short* __restrict__ packed,
                             double* __restrict__ ws_sum,
                             unsigned long long* __restrict__ ws_cnt)
{
    int t = blockIdx.x * 256 + threadIdx.x;      // 0 .. 32*5*64-1
    if (t == 0) { ws_sum[0] = 0.0; ws_cnt[0] = 0ull; }
    if (t >= 32 * NT_TILES * 64) return;
    int s2 = t / (NT_TILES * 64);
    int r  = t - s2 * (NT_TILES * 64);
    int nt = r >> 6;
    int l  = r & 63;
    int c  = nt * 32 + (l & 31);
    int k  = s2 * 16 + (l >> 5) * 8;
    unsigned short v[8];
#pragma unroll
    for (int j = 0; j < 8; ++j)
        v[j] = (c < NUM_CLS) ? (unsigned short)f2bf(cls[c * D_DIM + k + j]) : (unsigned short)0;
    u32x4 w;
#pragma unroll
    for (int q = 0; q < 4; ++q)
        w[q] = (unsigned int)v[2 * q] | ((unsigned int)v[2 * q + 1] << 16);
    *(u32x4*)(packed + (size_t)(s2 * NT_TILES + nt) * 512 + (size_t)l * 8) = w;
}

__global__ __launch_bounds__(256, 2)
void rsl_mfma(const float* __restrict__ pred,
              const unsigned short* __restrict__ packed,
              const int*   __restrict__ idx,
              const int*   __restrict__ lut,
              double* __restrict__ ws_sum,
              unsigned long long* __restrict__ ws_cnt)
{
    // LDS: pred [16 dims][256 px] fp32 16KB x2 + cls [5][512] ushort 5KB x2 = 42KB
    __shared__ float          sP[2][16][256];
    __shared__ unsigned short sC[2][NT_TILES][512];

    const int lane = threadIdx.x & 63;
    const int wid  = threadIdx.x >> 6;
    const int col  = lane & 31;      // A-frag pixel row / C-D class col
    const int hi   = lane >> 5;      // k-half (A/B frags) / pixel-row offset (C/D)

    const int pixbase = blockIdx.x * 256;        // never straddles b (65536%256==0)
    const int b  = pixbase >> 16;
    const int p0 = pixbase & 0xFFFF;
    const float* predb = pred + (size_t)b * D_DIM * HW_DIM + p0;

    f32x16 acc[2][NT_TILES] = {};

// stage pred K-tile ss (16 dims x 256 px) -> buffer q: 16 DMA ops (4/wave),
// each 1 KB CONTIGUOUS (one dim, 256 px).
#define STAGEP(ss, q) do { \
    _Pragma("unroll") \
    for (int tt = 0; tt < 4; ++tt) { \
        const int d_ = wid * 4 + tt; \
        GLOAD16(predb + (size_t)((ss) * 16 + d_) * HW_DIM + lane * 4, &sP[q][d_][0]); \
    } } while (0)

// stage cls K-tile ss -> buffer q: 5 DMA ops, each 1 KB contiguous
#define STAGEC(ss, q) do { \
    for (int nt = wid; nt < NT_TILES; nt += 4) \
        GLOAD16(packed + (size_t)((ss) * NT_TILES + nt) * 512 + (size_t)lane * 8, \
                &sC[q][nt][0]); \
    } while (0)

    // ---- prologue: stage s=0 ----
    STAGEP(0, 0);
    STAGEC(0, 0);
    __syncthreads();

    for (int s = 0; s < 32; ++s) {
        const int cur = s & 1;
        // ---- stage s+1 into the other buffer (async DMA) ----
        if (s < 31) {
            STAGEP(s + 1, cur ^ 1);
            STAGEC(s + 1, cur ^ 1);
        }

        // ---- compute: wave covers px [wid*64, wid*64+64) = 2 m-tiles of 32 ----
        bf16x8 pf[2];
#pragma unroll
        for (int mt = 0; mt < 2; ++mt)
#pragma unroll
            for (int j = 0; j < 8; ++j)
                pf[mt][j] = f2bf(sP[cur][hi * 8 + j][wid * 64 + mt * 32 + col]);  // 2-way = free

#pragma unroll
        for (int nt = 0; nt < NT_TILES; ++nt) {
            bf16x8 cf = *(const bf16x8*)&sC[cur][nt][lane * 8];
#pragma unroll
            for (int mt = 0; mt < 2; ++mt)
                acc[mt][nt] = __builtin_amdgcn_mfma_f32_32x32x16_bf16(pf[mt], cf, acc[mt][nt], 0, 0, 0);
        }
        __syncthreads();
    }

    // ---- epilogue (R5-verified). C/D: class = nt*32+col, pixel row = (r&3)+8*(r>>2)+4*hi ----
    const float invT = 1.0f / 0.07f;
    float local_sum = 0.f;
    int   local_cnt = 0;
#pragma unroll
    for (int mt = 0; mt < 2; ++mt) {
#pragma unroll
        for (int r = 0; r < 16; ++r) {
            const int prow = (r & 3) + 8 * (r >> 2) + 4 * hi;
            const int pixg = pixbase + wid * 64 + mt * 32 + prow;
            const int lab  = lut[idx[pixg]];
            const bool valid = (lab != IGNORE_L);

            float m = -1e30f;
#pragma unroll
            for (int nt = 0; nt < NT_TILES; ++nt) {
                int c = nt * 32 + col;
                float v = (c < NUM_CLS) ? acc[mt][nt][r] : -1e30f;
                m = fmaxf(m, v);
            }
#pragma unroll
            for (int o = 16; o >= 1; o >>= 1) m = fmaxf(m, __shfl_xor(m, o));

            float ssum = 0.f, slab = 0.f;
#pragma unroll
            for (int nt = 0; nt < NT_TILES; ++nt) {
                int c = nt * 32 + col;
                if (c < NUM_CLS) {
                    float v = acc[mt][nt][r];
                    ssum += __expf((v - m) * invT);
                    slab += (c == lab) ? v : 0.f;
                }
            }
#pragma unroll
            for (int o = 16; o >= 1; o >>= 1) {
                ssum += __shfl_xor(ssum, o);
                slab += __shfl_xor(slab, o);
            }
            if (col == 0 && valid) {
                local_sum += (m - slab) * invT + __logf(ssum);
                local_cnt += 1;
            }
        }
    }

    // wave(64) reduce -> block -> global atomics
#pragma unroll
    for (int o = 32; o >= 1; o >>= 1) {
        local_sum += __shfl_down(local_sum, o);
        local_cnt += __shfl_down(local_cnt, o);
    }
    __shared__ float sv[4];
    __shared__ int   sc[4];
    if (lane == 0) { sv[wid] = local_sum; sc[wid] = local_cnt; }
    __syncthreads();
    if (threadIdx.x == 0) {
        float tv = sv[0] + sv[1] + sv[2] + sv[3];
        int   tc = sc[0] + sc[1] + sc[2] + sc[3];
        atomicAdd(ws_sum, (double)tv);
        atomicAdd(ws_cnt, (unsigned long long)tc);
    }
}

__global__ void rsl_final(const double* __restrict__ ws_sum,
                          const unsigned long long* __restrict__ ws_cnt,
                          float* __restrict__ out)
{
    if (threadIdx.x == 0) {
        double c = (double)ws_cnt[0];
        out[0] = (float)(ws_sum[0] / (c > 0.0 ? c : 1.0));
    }
}

extern "C" void kernel_launch(void* const* d_in, const int* in_sizes, int n_in,
                              void* d_out, int out_size, void* d_ws, size_t ws_size,
                              hipStream_t stream)
{
    const float* pred = (const float*)d_in[0];   // (4, 512, 256, 256) fp32
    const float* cls  = (const float*)d_in[1];   // (150, 512) fp32
    const int*   idx  = (const int*)d_in[2];     // (4, 1, 256, 256) int32
    const int*   lut  = (const int*)d_in[3];     // (512,) int32
    float* out = (float*)d_out;

    double* wsd = (double*)d_ws;
    unsigned long long* wsc = (unsigned long long*)((char*)d_ws + 8);
    unsigned short* packed = (unsigned short*)((char*)d_ws + 1024);  // 160 KB

    rsl_pack_cls<<<40, 256, 0, stream>>>(cls, packed, wsd, wsc);

    const int total = 4 * HW_DIM;                 // 262144 pixels
    rsl_mfma<<<total / 256, 256, 0, stream>>>(pred, packed, idx, lut, wsd, wsc);
    rsl_final<<<1, 64, 0, stream>>>(wsd, wsc, out);
}